// Round 7
// baseline (56.111 us; speedup 1.0000x reference)
//
#include <hip/hip_runtime.h>

#define CLS 8
#define BATCH 8
#define BPB 128                 // blocks per batch -> 1024 blocks total
#define TPX 512                 // pixels per tile
#define NSLICE 8
#define LOG2E 1.442695040888963f
#define LN2   0.693147180559945f

struct WS {
    float    S[NSLICE][BATCH][64];   // class-conditional channel sums
    float    n[NSLICE][BATCH][CLS];  // class pixel counts
    float    lse[NSLICE];            // sum of log2(sum_i exp2(p_i*log2e))
    unsigned cnt;                    // completion ticket
};

__device__ __forceinline__ float wave_reduce(float v) {
#pragma unroll
    for (int off = 32; off > 0; off >>= 1) v += __shfl_xor(v, off);
    return v;
}

// async 16B-per-lane global -> LDS; lds base wave-uniform, lane writes base+lane*16
__device__ __forceinline__ void gload16(const void* g, void* l) {
    __builtin_amdgcn_global_load_lds(
        (const __attribute__((address_space(1))) unsigned int*)g,
        (__attribute__((address_space(3))) unsigned int*)l, 16, 0, 0);
}

__global__ __launch_bounds__(256, 4) void jce_fused(
    const float* __restrict__ pred, const int* __restrict__ tgt,
    const float* __restrict__ w, float* __restrict__ out,
    WS* ws, int N)
{
    __shared__ float predT[2][CLS][TPX];   // 32 KB, double-buffered pred tile
    __shared__ int   tgtT[2][TPX];         // 4 KB
    __shared__ float redS[4][64];
    __shared__ float redl[4];
    __shared__ int   redc[4][CLS];
    __shared__ float epi[576];             // epilogue: eS[8][64] + eN[8][8]
    __shared__ float eLse, eCe;
    __shared__ int   lastFlag;

    const int tid  = threadIdx.x;
    const int b    = blockIdx.x & (BATCH - 1);
    const int blk  = blockIdx.x >> 3;          // 0..127
    const int wv   = tid >> 6;
    const int lane = tid & 63;
    const float* pb = pred + (size_t)b * CLS * N;
    const int*   tb = tgt  + (size_t)b * N;
    const int nt = N / (BPB * TPX);            // 4 tiles per block

    float acc[64];                             // acc[i*8+k] = sum_{p: t=k} pred[i]
#pragma unroll
    for (int j = 0; j < 64; ++j) acc[j] = 0.f;
    float accl = 0.f;
    int cls_cnt[CLS] = {0, 0, 0, 0, 0, 0, 0, 0};

    // stage tile tt into buffer bf: 16 pred instrs (4/wave) + 2 tgt instrs (waves 0,1)
#define STAGE(bf, tt) do {                                                        \
        const int _base = (blk * nt + (tt)) * TPX;                                \
        _Pragma("unroll")                                                         \
        for (int _q = 0; _q < 4; ++_q) {                                          \
            const int _j = wv * 4 + _q;                                           \
            const int _c = _j >> 1, _h = _j & 1;                                  \
            gload16(pb + (size_t)_c * N + _base + _h * 256 + lane * 4,            \
                    &predT[bf][_c][_h * 256]);                                    \
        }                                                                         \
        if (wv < 2)                                                               \
            gload16(tb + _base + wv * 256 + lane * 4, &tgtT[bf][wv * 256]);       \
    } while (0)

    // prologue: stage tile 0, drain (syncthreads emits vmcnt(0))
    STAGE(0, 0);
    __syncthreads();

    int cur = 0;
    for (int t = 0; t < nt; ++t) {
        if (t + 1 < nt) STAGE(cur ^ 1, t + 1);   // next tile in flight during compute

#pragma unroll
        for (int e = 0; e < 2; ++e) {
            const int px = tid + e * 256;
            float pc[CLS];
#pragma unroll
            for (int c = 0; c < CLS; ++c) pc[c] = predT[cur][c][px];
            const int tv = tgtT[cur][px];

            float s = 0.f;
#pragma unroll
            for (int i = 0; i < CLS; ++i) s += exp2f(pc[i] * LOG2E);
            accl += log2f(s);

#pragma unroll
            for (int k = 0; k < CLS; ++k) {
                const bool isk = (tv == k);
                cls_cnt[k] += __popcll(__ballot(isk));
                const float pm = isk ? 1.f : 0.f;
#pragma unroll
                for (int i = 0; i < CLS; ++i)
                    acc[i * 8 + k] = fmaf(pm, pc[i], acc[i * 8 + k]);
            }
        }

        __syncthreads();   // drains next-tile loads (in flight since phase start)
        cur ^= 1;
    }
#undef STAGE

    // split-vector butterfly: reduce 64-entry register vector across 64 lanes;
    // lane l ends holding the wave-total of entry bitrev6(l)
#pragma unroll
    for (int s6 = 0; s6 < 6; ++s6) {
        const int d = 1 << s6;
        const int half = 32 >> s6;
        const bool hi = (lane & d) != 0;
#pragma unroll
        for (int j = 0; j < half; ++j) {
            const float keep = hi ? acc[j + half] : acc[j];
            const float send = hi ? acc[j] : acc[j + half];
            acc[j] = keep + __shfl_xor(send, d);
        }
    }
    const int e6 = ((lane & 1) << 5) | ((lane & 2) << 3) | ((lane & 4) << 1) |
                   ((lane & 8) >> 1) | ((lane & 16) >> 3) | ((lane & 32) >> 5);

    redS[wv][e6] = acc[0];
    const float lsum = wave_reduce(accl);
    if (lane == 0) {
        redl[wv] = lsum;
#pragma unroll
        for (int k = 0; k < CLS; ++k) redc[wv][k] = cls_cnt[k];
    }
    __syncthreads();

    const int sl = blk & (NSLICE - 1);
    if (tid < 64) {
        const float v = redS[0][tid] + redS[1][tid] + redS[2][tid] + redS[3][tid];
        atomicAdd(&ws->S[sl][b][tid], v);
    } else if (tid < 64 + CLS) {
        const int k = tid - 64;
        const float v = (float)(redc[0][k] + redc[1][k] + redc[2][k] + redc[3][k]);
        atomicAdd(&ws->n[sl][b][k], v);
    } else if (tid == 64 + CLS) {
        atomicAdd(&ws->lse[sl], redl[0] + redl[1] + redl[2] + redl[3]);
    }

    // ---- last-block-done epilogue ----
    __syncthreads();
    if (tid == 0) {
        __threadfence();
        const unsigned t = atomicAdd(&ws->cnt, 1u);
        lastFlag = (t == gridDim.x - 1) ? 1 : 0;
    }
    __syncthreads();
    if (!lastFlag) return;
    __threadfence();

    // epi[0..511] = eS[b][64]; epi[512..575] = eN[b][8]
    for (int j = tid; j < 577; j += 256) {
        float s = 0.f;
        if (j < 512) {
            const int bb = j >> 6, ee = j & 63;
#pragma unroll
            for (int s8 = 0; s8 < NSLICE; ++s8) s += atomicAdd(&ws->S[s8][bb][ee], 0.f);
            epi[j] = s;
        } else if (j < 576) {
            const int q = j - 512, bb = q >> 3, k = q & 7;
#pragma unroll
            for (int s8 = 0; s8 < NSLICE; ++s8) s += atomicAdd(&ws->n[s8][bb][k], 0.f);
            epi[j] = s;
        } else {
#pragma unroll
            for (int s8 = 0; s8 < NSLICE; ++s8) s += atomicAdd(&ws->lse[s8], 0.f);
            eLse = s * LN2;
        }
    }
    __syncthreads();

    // ce = (sum lse - sum_b trace(S_b)) / (B*N)
    if (tid < 64) {
        const int bb = tid >> 3, kk = tid & 7;
        float tv = epi[bb * 64 + kk * 9];
        tv = wave_reduce(tv);
        if (tid == 0) eCe = (eLse - tv) / ((float)BATCH * (float)N);
    }
    __syncthreads();

    // j[b] = -sum_{i!=k} w[i,k]*log(0.5 + 0.5*(A[i,i]-A[i,k])); out = j + ce
    const int i = lane >> 3, k = lane & 7;
#pragma unroll
    for (int r = 0; r < 2; ++r) {
        const int bb = wv * 2 + r;             // 4 waves x 2 batches
        const float A    = epi[bb * 64 + lane] / epi[512 + bb * 8 + k];
        const float diag = epi[bb * 64 + i * 9] / epi[512 + bb * 8 + i];
        float term = 0.f;
        if (i != k)
            term = w[lane] * (log2f(0.5f + 0.5f * (diag - A)) * LN2);
        term = wave_reduce(term);
        if (lane == 0) out[bb] = -term + eCe;
    }
}

extern "C" void kernel_launch(void* const* d_in, const int* in_sizes, int n_in,
                              void* d_out, int out_size, void* d_ws, size_t ws_size,
                              hipStream_t stream) {
    const float* pred = (const float*)d_in[0];
    const int*   tgt  = (const int*)d_in[1];
    const float* w    = (const float*)d_in[2];
    float* out = (float*)d_out;

    const int N = in_sizes[1] / BATCH;        // H*W = 262144
    WS* ws = (WS*)d_ws;

    hipMemsetAsync(ws, 0, sizeof(WS), stream);
    jce_fused<<<dim3(BATCH * BPB), dim3(256), 0, stream>>>(pred, tgt, w, out, ws, N);
}